// Round 3
// baseline (4076.814 us; speedup 1.0000x reference)
//
#include <hip/hip_runtime.h>
#include <hip/hip_bf16.h>
#include <math.h>

#define B_ 4
#define T_ 2048
#define C_ 2048
#define H_ 32
#define BT_ 8192
#define WELE 4194304L            // 2048*2048
#define BTC  16777216L           // 8192*2048

typedef unsigned short u16;
typedef __bf16 bf16x8 __attribute__((ext_vector_type(8)));
typedef float  f32x4  __attribute__((ext_vector_type(4)));

__device__ __forceinline__ u16 f2b(float f){
  __hip_bfloat16 h = __float2bfloat16(f);
  return *reinterpret_cast<u16*>(&h);
}
__device__ __forceinline__ float b2f(u16 u){
  __hip_bfloat16 h; *reinterpret_cast<u16*>(&h) = u;
  return __bfloat162float(h);
}
__device__ __forceinline__ float bits2f(unsigned u){
  union { unsigned u; float f; } c; c.u = u; return c.f;
}

__device__ __forceinline__ void async_copy16(const u16* gptr, u16* lptr){
  __builtin_amdgcn_global_load_lds(
      (const __attribute__((address_space(1))) unsigned int*)gptr,
      (__attribute__((address_space(3))) unsigned int*)lptr,
      16, 0, 0);
}

// unpack 8 consecutive bf16 at gp into 8 floats (addr may be wave-uniform)
__device__ __forceinline__ void unpack8(const u16* __restrict__ gp, float* out){
  const uint4 raw = *(const uint4*)gp;
  out[0] = bits2f(raw.x << 16); out[1] = bits2f(raw.x & 0xffff0000u);
  out[2] = bits2f(raw.y << 16); out[3] = bits2f(raw.y & 0xffff0000u);
  out[4] = bits2f(raw.z << 16); out[5] = bits2f(raw.z & 0xffff0000u);
  out[6] = bits2f(raw.w << 16); out[7] = bits2f(raw.w & 0xffff0000u);
}

// ---------------- weight prep ----------------
// fp32 (WELE) -> bf16
__global__ __launch_bounds__(256) void cvt1(const float* __restrict__ src,
                                            u16* __restrict__ dst)
{
  const long i = ((long)blockIdx.x*256 + threadIdx.x)*4;
  const float4 v = *(const float4*)(src + i);
  ushort4 o = { f2b(v.x), f2b(v.y), f2b(v.z), f2b(v.w) };
  *(ushort4*)(dst + i) = o;
}

// dst (Npad x R) bf16 = transpose of src (R x Cc) f32, zero-padded rows n>=Cc
__global__ __launch_bounds__(256) void tposeA(const float* __restrict__ src,
    u16* __restrict__ dst, int R, int Cc, int Npad)
{
  const long idx = (long)blockIdx.x*256 + threadIdx.x;
  if (idx >= (long)Npad * R) return;
  const int n = (int)(idx / R), rr = (int)(idx % R);
  float vv = (n < Cc) ? src[(long)rr * Cc + n] : 0.f;
  dst[idx] = f2b(vv);
}

// w2t[f][c][d] = w2[f][d][c]   (5,32,2048) -> 5 x (2048 x 32)
__global__ __launch_bounds__(256) void tposeW2(const float* __restrict__ src,
                                               u16* __restrict__ dst)
{
  const long idx = (long)blockIdx.x*256 + threadIdx.x; // < 5*2048*32
  const int f = (int)(idx / 65536);
  const int rem = (int)(idx % 65536);
  const int c = rem >> 5, d = rem & 31;
  dst[idx] = f2b(src[((long)f*32 + d)*2048 + c]);
}

// ---------------- token shift / xxx ----------------
__global__ __launch_bounds__(256) void mixA(const float* __restrict__ x,
    const float* __restrict__ maax, u16* __restrict__ xxx, u16* __restrict__ xxb)
{
  const long i = ((long)blockIdx.x*256 + threadIdx.x) * 4;
  const int c   = (int)(i & (C_-1));
  const int tok = (int)(i >> 11);
  const int t   = tok & (T_-1);
  const float4 xc = *(const float4*)(x + i);
  float4 xp = make_float4(0.f,0.f,0.f,0.f);
  if (t > 0) xp = *(const float4*)(x + i - C_);
  const float4 mx = *(const float4*)(maax + c);
  const float xx0 = xp.x - xc.x, xx1 = xp.y - xc.y;
  const float xx2 = xp.z - xc.z, xx3 = xp.w - xc.w;
  ushort4 ox = { f2b(xx0), f2b(xx1), f2b(xx2), f2b(xx3) };
  ushort4 o3 = { f2b(fmaf(xx0, mx.x, xc.x)), f2b(fmaf(xx1, mx.y, xc.y)),
                 f2b(fmaf(xx2, mx.z, xc.z)), f2b(fmaf(xx3, mx.w, xc.w)) };
  *(ushort4*)(xxb + i) = ox;
  *(ushort4*)(xxx + i) = o3;
}

// ---------------- GEMM: C[m][n] = sum_k A[m][k]*B[n][k], bf16 MFMA ----------------
enum { EPI_BF16=0, EPI_TANH=1, EPI_SILU=2, EPI_MIX=3, EPI_DECAY=4, EPI_F32=5 };

template<int EPI>
__global__ __launch_bounds__(256) void gemm_bt(
    const u16* __restrict__ A, int lda,
    const u16* __restrict__ Bm, int ldb, int K,
    void* __restrict__ Out, int ldo,
    const float* __restrict__ aux0, const u16* __restrict__ aux1,
    const float* __restrict__ aux2)
{
  __shared__ u16 As[128*32];
  __shared__ u16 Bs[128*32];
  const int tid = threadIdx.x;
  const int w = tid >> 6, lane = tid & 63;
  const int m0 = blockIdx.y * 128, n0 = blockIdx.x * 128;
  const int wm = w >> 1, wn = w & 1;
  const int rowA = lane >> 2, chunk = lane & 3;
  f32x4 acc[4][4];
  #pragma unroll
  for (int i=0;i<4;i++)
    #pragma unroll
    for (int j=0;j<4;j++) acc[i][j] = (f32x4){0.f,0.f,0.f,0.f};

  for (int k0 = 0; k0 < K; k0 += 32){
    #pragma unroll
    for (int s=0; s<2; s++){
      const int seg = w*2 + s;
      const int row = seg*16 + rowA;
      async_copy16(A  + (long)(m0+row)*lda + k0 + chunk*8, As + seg*512);
      async_copy16(Bm + (long)(n0+row)*ldb + k0 + chunk*8, Bs + seg*512);
    }
    __syncthreads();
    const int kq = (lane >> 4) * 8;
    const int lr16 = lane & 15;
    bf16x8 af[4], bfr[4];
    #pragma unroll
    for (int mt=0; mt<4; mt++)
      af[mt] = *(const bf16x8*)(As + (wm*64 + mt*16 + lr16)*32 + kq);
    #pragma unroll
    for (int nt=0; nt<4; nt++)
      bfr[nt] = *(const bf16x8*)(Bs + (wn*64 + nt*16 + lr16)*32 + kq);
    #pragma unroll
    for (int mt=0; mt<4; mt++)
      #pragma unroll
      for (int nt=0; nt<4; nt++)
        acc[mt][nt] = __builtin_amdgcn_mfma_f32_16x16x32_bf16(af[mt], bfr[nt], acc[mt][nt], 0, 0, 0);
    __syncthreads();
  }

  const int cr = lane & 15, cq = lane >> 4;
  #pragma unroll
  for (int mt=0; mt<4; mt++){
    #pragma unroll
    for (int nt=0; nt<4; nt++){
      #pragma unroll
      for (int rr=0; rr<4; rr++){
        const int row = m0 + wm*64 + mt*16 + cq*4 + rr;
        const int col = n0 + wn*64 + nt*16 + cr;
        const long oi = (long)row*ldo + col;
        const float val = acc[mt][nt][rr];
        if constexpr (EPI == EPI_F32){
          ((float*)Out)[oi] = val;
        } else if constexpr (EPI == EPI_BF16){
          ((u16*)Out)[oi] = f2b(val);
        } else if constexpr (EPI == EPI_TANH){
          ((u16*)Out)[oi] = f2b(tanhf(val));
        } else if constexpr (EPI == EPI_SILU){
          ((u16*)Out)[oi] = f2b(val / (1.f + expf(-val)));
        } else if constexpr (EPI == EPI_MIX){
          const float xv  = aux0[oi];
          const float xxv = b2f(aux1[oi]);
          ((u16*)Out)[oi] = f2b(fmaf(xxv, aux2[col] + val, xv));
        } else { // EPI_DECAY: decay = exp(-exp(val + time_decay[col]))
          ((float*)Out)[oi] = expf(-expf(val + aux0[col]));
        }
      }
    }
  }
}

// ---------------- WKV6 scan + groupnorm + *g ----------------
// One block per (b,h); 4 waves split the j (key) dim, 16 j each.
// Per-step path is pure VALU: r/k/d read as wave-uniform global vectors
// (one broadcast fetch), v as a coalesced per-lane load. Cross-wave
// combine + groupnorm deferred to once per 16-step chunk (2 barriers/chunk
// vs 2048 in the old version, which was 5.5% VALUBusy latency-bound).
__global__ __launch_bounds__(256, 1) void wkv(
    const u16* __restrict__ r, const u16* __restrict__ k, const u16* __restrict__ v,
    const float* __restrict__ dec, const float* __restrict__ faaaa,
    const float* __restrict__ gam, const float* __restrict__ bet,
    const u16* __restrict__ g, u16* __restrict__ act)
{
  const int blk = blockIdx.x;
  const int b = blk >> 5, h = blk & 31;
  const int tid = threadIdx.x;
  const int jg = tid >> 6, lane = tid & 63;
  const int hoff = h * 64;

  float S[16];
  #pragma unroll
  for (int jj=0;jj<16;jj++) S[jj] = 0.f;
  float u[16];
  #pragma unroll
  for (int jj=0;jj<16;jj++) u[jj] = faaaa[hoff + jg*16 + jj];
  const float gmv = gam[hoff + lane], btv = bet[hoff + lane];

  __shared__ float yred[16][4][64];   // [t-in-chunk][wave][i]

  const long base0 = ((long)b * T_) * C_ + hoff;
  const int joff = jg * 16;

  for (int t0 = 0; t0 < T_; t0 += 16){
    __syncthreads();                    // guard yred reuse across chunks
    #pragma unroll 4
    for (int tt = 0; tt < 16; tt++){
      const long rowoff = base0 + (long)(t0 + tt) * C_;
      float rv[16], kv[16], dv[16];
      unpack8(r + rowoff + joff,     rv);
      unpack8(r + rowoff + joff + 8, rv + 8);
      unpack8(k + rowoff + joff,     kv);
      unpack8(k + rowoff + joff + 8, kv + 8);
      #pragma unroll
      for (int q=0;q<4;q++)
        *(float4*)(dv + q*4) = *(const float4*)(dec + rowoff + joff + q*4);
      const float vi = b2f(v[rowoff + lane]);

      float yp = 0.f;
      #pragma unroll
      for (int jj=0;jj<16;jj++){
        const float p = kv[jj] * vi;
        yp = fmaf(rv[jj], fmaf(u[jj], p, S[jj]), yp);
        S[jj] = fmaf(dv[jj], S[jj], p);
      }
      yred[tt][jg][lane] = yp;
    }
    __syncthreads();
    // combine partials + groupnorm + *g : each wave handles 4 timesteps
    #pragma unroll
    for (int q=0;q<4;q++){
      const int tt = jg*4 + q;
      const float y = yred[tt][0][lane] + yred[tt][1][lane]
                    + yred[tt][2][lane] + yred[tt][3][lane];
      float s1 = y, s2 = y*y;
      #pragma unroll
      for (int off=32; off>0; off>>=1){
        s1 += __shfl_xor(s1, off, 64);
        s2 += __shfl_xor(s2, off, 64);
      }
      const float mean = s1 * (1.f/64.f);
      const float var  = s2 * (1.f/64.f) - mean*mean;
      const float yn   = (y - mean) * rsqrtf(var + 6.4e-4f);  // EPS = 1e-5*8^2
      const long  oi   = base0 + (long)(t0 + tt) * C_ + lane;
      const float o    = (yn * gmv + btv) * b2f(g[oi]);
      act[oi] = f2b(o);
    }
  }
}

extern "C" void kernel_launch(void* const* d_in, const int* in_sizes, int n_in,
                              void* d_out, int out_size, void* d_ws, size_t ws_size,
                              hipStream_t stream)
{
  const float* x     = (const float*)d_in[0];
  const float* tmx   = (const float*)d_in[1];
  const float* maaf[5] = {(const float*)d_in[2], (const float*)d_in[3],
                          (const float*)d_in[4], (const float*)d_in[5],
                          (const float*)d_in[6]};
  const float* w1    = (const float*)d_in[7];
  const float* w2    = (const float*)d_in[8];
  const float* td    = (const float*)d_in[9];
  const float* tdw1  = (const float*)d_in[10];
  const float* tdw2  = (const float*)d_in[11];
  const float* faaaa = (const float*)d_in[12];
  const float* Wmat[5] = {(const float*)d_in[13], (const float*)d_in[14],
                          (const float*)d_in[15], (const float*)d_in[16],
                          (const float*)d_in[17]};   // W_r, W_k, W_v, W_g, W_o
  const float* ln_g  = (const float*)d_in[18];
  const float* ln_b  = (const float*)d_in[19];

  // ---- workspace layout: ~151.6 MB total ----
  char* p = (char*)d_ws;
  auto take = [&](size_t bytes)->char*{
    char* q = p; p += (bytes + 255) & ~(size_t)255; return q;
  };
  u16*   w1t  = (u16*)take(256L*2048*2);     // (256 x 2048), rows>=160 zero
  u16*   w2t  = (u16*)take(5L*2048*32*2);    // 5 x (2048 x 32)
  u16*   wd1t = (u16*)take(128L*2048*2);     // (128 x 2048), rows>=64 zero
  u16*   wd2t = (u16*)take(2048L*64*2);      // (2048 x 64)
  u16*   wcur = (u16*)take(WELE*2);          // current weight, bf16 (reused 5x)
  u16*   xxx  = (u16*)take(BTC*2);           // xxx; aliased as mixbuf after a-GEMM
  u16*   xxb  = (u16*)take(BTC*2);           // xx;  aliased as rbuf (r done last)
  u16*   abuf = (u16*)take((long)BT_*256*2); // a = tanh(xxx@w1)
  u16*   hbuf = (u16*)take((long)BT_*128*2); // tanh(xw@tdw1)
  u16*   kbuf = (u16*)take(BTC*2);           // aliased as act (safe: see wkv notes)
  u16*   vbuf = (u16*)take(BTC*2);
  u16*   gbuf = (u16*)take(BTC*2);
  u16*   mixbuf = xxx;            // xxx dead after a-GEMM
  u16*   rbuf   = xxb;            // xxb dead after mix-r epilogue
  u16*   act    = kbuf;           // block (b,h) reads its k rows before writing them
  float* dcy    = (float*)d_out;  // fp32 decay; d_out dead until final GEMM
  (void)in_sizes; (void)n_in; (void)out_size; (void)ws_size;

  // small-weight prep
  tposeA <<<2048, 256, 0, stream>>>(w1,   w1t,  2048, 160, 256);
  tposeW2<<<1280, 256, 0, stream>>>(w2,   w2t);
  tposeA <<<1024, 256, 0, stream>>>(tdw1, wd1t, 2048, 64, 128);
  tposeA <<<512,  256, 0, stream>>>(tdw2, wd2t, 64, 2048, 2048);

  // token shift
  mixA<<<16384, 256, 0, stream>>>(x, tmx, xxx, xxb);

  // a = tanh(xxx @ w1)   (M=8192, N=256(pad), K=2048)
  gemm_bt<EPI_TANH><<<dim3(2,64), 256, 0, stream>>>(xxx, 2048, w1t, 2048, 2048,
      abuf, 256, nullptr, nullptr, nullptr);

  // ---- f = w (decay path) ----
  gemm_bt<EPI_MIX><<<dim3(16,64), 256, 0, stream>>>(abuf + 0*32, 256,
      w2t + 0L*65536, 32, 32, mixbuf, 2048, x, xxb, maaf[0]);
  gemm_bt<EPI_TANH><<<dim3(1,64), 256, 0, stream>>>(mixbuf, 2048, wd1t, 2048, 2048,
      hbuf, 128, nullptr, nullptr, nullptr);
  gemm_bt<EPI_DECAY><<<dim3(16,64), 256, 0, stream>>>(hbuf, 128, wd2t, 64, 64,
      dcy, 2048, td, nullptr, nullptr);

  // ---- f = k ----
  gemm_bt<EPI_MIX><<<dim3(16,64), 256, 0, stream>>>(abuf + 1*32, 256,
      w2t + 1L*65536, 32, 32, mixbuf, 2048, x, xxb, maaf[1]);
  cvt1<<<4096, 256, 0, stream>>>(Wmat[1], wcur);
  gemm_bt<EPI_BF16><<<dim3(16,64), 256, 0, stream>>>(mixbuf, 2048, wcur, 2048, 2048,
      kbuf, 2048, nullptr, nullptr, nullptr);

  // ---- f = v ----
  gemm_bt<EPI_MIX><<<dim3(16,64), 256, 0, stream>>>(abuf + 2*32, 256,
      w2t + 2L*65536, 32, 32, mixbuf, 2048, x, xxb, maaf[2]);
  cvt1<<<4096, 256, 0, stream>>>(Wmat[2], wcur);
  gemm_bt<EPI_BF16><<<dim3(16,64), 256, 0, stream>>>(mixbuf, 2048, wcur, 2048, 2048,
      vbuf, 2048, nullptr, nullptr, nullptr);

  // ---- f = g ----
  gemm_bt<EPI_MIX><<<dim3(16,64), 256, 0, stream>>>(abuf + 4*32, 256,
      w2t + 4L*65536, 32, 32, mixbuf, 2048, x, xxb, maaf[4]);
  cvt1<<<4096, 256, 0, stream>>>(Wmat[3], wcur);
  gemm_bt<EPI_SILU><<<dim3(16,64), 256, 0, stream>>>(mixbuf, 2048, wcur, 2048, 2048,
      gbuf, 2048, nullptr, nullptr, nullptr);

  // ---- f = r (last: frees xxb for rbuf) ----
  gemm_bt<EPI_MIX><<<dim3(16,64), 256, 0, stream>>>(abuf + 3*32, 256,
      w2t + 3L*65536, 32, 32, mixbuf, 2048, x, xxb, maaf[3]);
  cvt1<<<4096, 256, 0, stream>>>(Wmat[0], wcur);
  gemm_bt<EPI_BF16><<<dim3(16,64), 256, 0, stream>>>(mixbuf, 2048, wcur, 2048, 2048,
      rbuf, 2048, nullptr, nullptr, nullptr);

  // ---- wkv scan + groupnorm + *g ----
  wkv<<<128, 256, 0, stream>>>(rbuf, kbuf, vbuf, dcy, faaaa, ln_g, ln_b, gbuf, act);

  // ---- out = act @ W_o^T (fp32) ----
  cvt1<<<4096, 256, 0, stream>>>(Wmat[4], wcur);
  gemm_bt<EPI_F32><<<dim3(16,64), 256, 0, stream>>>(act, 2048, wcur, 2048, 2048,
      d_out, 2048, nullptr, nullptr, nullptr);
}

// Round 4
// 1618.897 us; speedup vs baseline: 2.5183x; 2.5183x over previous
//
#include <hip/hip_runtime.h>
#include <hip/hip_bf16.h>
#include <math.h>

#define B_ 4
#define T_ 2048
#define C_ 2048
#define H_ 32
#define BT_ 8192
#define WELE 4194304L            // 2048*2048
#define BTC  16777216L           // 8192*2048

typedef unsigned short u16;
typedef __bf16 bf16x8 __attribute__((ext_vector_type(8)));
typedef float  f32x4  __attribute__((ext_vector_type(4)));

__device__ __forceinline__ u16 f2b(float f){
  __hip_bfloat16 h = __float2bfloat16(f);
  return *reinterpret_cast<u16*>(&h);
}
__device__ __forceinline__ float b2f(u16 u){
  __hip_bfloat16 h; *reinterpret_cast<u16*>(&h) = u;
  return __bfloat162float(h);
}
__device__ __forceinline__ float bits2f(unsigned u){
  union { unsigned u; float f; } c; c.u = u; return c.f;
}

__device__ __forceinline__ void async_copy16(const u16* gptr, u16* lptr){
  __builtin_amdgcn_global_load_lds(
      (const __attribute__((address_space(1))) unsigned int*)gptr,
      (__attribute__((address_space(3))) unsigned int*)lptr,
      16, 0, 0);
}

// unpack 4 consecutive bf16 at gp into 4 floats
__device__ __forceinline__ void unpack4(const u16* __restrict__ gp, float* out){
  const uint2 raw = *(const uint2*)gp;
  out[0] = bits2f(raw.x << 16); out[1] = bits2f(raw.x & 0xffff0000u);
  out[2] = bits2f(raw.y << 16); out[3] = bits2f(raw.y & 0xffff0000u);
}

// ---------------- weight prep ----------------
// fp32 (WELE) -> bf16
__global__ __launch_bounds__(256) void cvt1(const float* __restrict__ src,
                                            u16* __restrict__ dst)
{
  const long i = ((long)blockIdx.x*256 + threadIdx.x)*4;
  const float4 v = *(const float4*)(src + i);
  ushort4 o = { f2b(v.x), f2b(v.y), f2b(v.z), f2b(v.w) };
  *(ushort4*)(dst + i) = o;
}

// dst (Npad x R) bf16 = transpose of src (R x Cc) f32, zero-padded rows n>=Cc
__global__ __launch_bounds__(256) void tposeA(const float* __restrict__ src,
    u16* __restrict__ dst, int R, int Cc, int Npad)
{
  const long idx = (long)blockIdx.x*256 + threadIdx.x;
  if (idx >= (long)Npad * R) return;
  const int n = (int)(idx / R), rr = (int)(idx % R);
  float vv = (n < Cc) ? src[(long)rr * Cc + n] : 0.f;
  dst[idx] = f2b(vv);
}

// w2t[f][c][d] = w2[f][d][c]   (5,32,2048) -> 5 x (2048 x 32)
__global__ __launch_bounds__(256) void tposeW2(const float* __restrict__ src,
                                               u16* __restrict__ dst)
{
  const long idx = (long)blockIdx.x*256 + threadIdx.x; // < 5*2048*32
  const int f = (int)(idx / 65536);
  const int rem = (int)(idx % 65536);
  const int c = rem >> 5, d = rem & 31;
  dst[idx] = f2b(src[((long)f*32 + d)*2048 + c]);
}

// ---------------- token shift / xxx ----------------
__global__ __launch_bounds__(256) void mixA(const float* __restrict__ x,
    const float* __restrict__ maax, u16* __restrict__ xxx, u16* __restrict__ xxb)
{
  const long i = ((long)blockIdx.x*256 + threadIdx.x) * 4;
  const int c   = (int)(i & (C_-1));
  const int tok = (int)(i >> 11);
  const int t   = tok & (T_-1);
  const float4 xc = *(const float4*)(x + i);
  float4 xp = make_float4(0.f,0.f,0.f,0.f);
  if (t > 0) xp = *(const float4*)(x + i - C_);
  const float4 mx = *(const float4*)(maax + c);
  const float xx0 = xp.x - xc.x, xx1 = xp.y - xc.y;
  const float xx2 = xp.z - xc.z, xx3 = xp.w - xc.w;
  ushort4 ox = { f2b(xx0), f2b(xx1), f2b(xx2), f2b(xx3) };
  ushort4 o3 = { f2b(fmaf(xx0, mx.x, xc.x)), f2b(fmaf(xx1, mx.y, xc.y)),
                 f2b(fmaf(xx2, mx.z, xc.z)), f2b(fmaf(xx3, mx.w, xc.w)) };
  *(ushort4*)(xxb + i) = ox;
  *(ushort4*)(xxx + i) = o3;
}

// ---------------- GEMM: C[m][n] = sum_k A[m][k]*B[n][k], bf16 MFMA ----------------
enum { EPI_BF16=0, EPI_TANH=1, EPI_SILU=2, EPI_MIX=3, EPI_DECAY=4, EPI_F32=5 };

template<int EPI>
__global__ __launch_bounds__(256) void gemm_bt(
    const u16* __restrict__ A, int lda,
    const u16* __restrict__ Bm, int ldb, int K,
    void* __restrict__ Out, int ldo,
    const float* __restrict__ aux0, const u16* __restrict__ aux1,
    const float* __restrict__ aux2)
{
  __shared__ u16 As[128*32];
  __shared__ u16 Bs[128*32];
  const int tid = threadIdx.x;
  const int w = tid >> 6, lane = tid & 63;
  const int m0 = blockIdx.y * 128, n0 = blockIdx.x * 128;
  const int wm = w >> 1, wn = w & 1;
  const int rowA = lane >> 2, chunk = lane & 3;
  f32x4 acc[4][4];
  #pragma unroll
  for (int i=0;i<4;i++)
    #pragma unroll
    for (int j=0;j<4;j++) acc[i][j] = (f32x4){0.f,0.f,0.f,0.f};

  for (int k0 = 0; k0 < K; k0 += 32){
    #pragma unroll
    for (int s=0; s<2; s++){
      const int seg = w*2 + s;
      const int row = seg*16 + rowA;
      async_copy16(A  + (long)(m0+row)*lda + k0 + chunk*8, As + seg*512);
      async_copy16(Bm + (long)(n0+row)*ldb + k0 + chunk*8, Bs + seg*512);
    }
    __syncthreads();
    const int kq = (lane >> 4) * 8;
    const int lr16 = lane & 15;
    bf16x8 af[4], bfr[4];
    #pragma unroll
    for (int mt=0; mt<4; mt++)
      af[mt] = *(const bf16x8*)(As + (wm*64 + mt*16 + lr16)*32 + kq);
    #pragma unroll
    for (int nt=0; nt<4; nt++)
      bfr[nt] = *(const bf16x8*)(Bs + (wn*64 + nt*16 + lr16)*32 + kq);
    #pragma unroll
    for (int mt=0; mt<4; mt++)
      #pragma unroll
      for (int nt=0; nt<4; nt++)
        acc[mt][nt] = __builtin_amdgcn_mfma_f32_16x16x32_bf16(af[mt], bfr[nt], acc[mt][nt], 0, 0, 0);
    __syncthreads();
  }

  const int cr = lane & 15, cq = lane >> 4;
  #pragma unroll
  for (int mt=0; mt<4; mt++){
    #pragma unroll
    for (int nt=0; nt<4; nt++){
      #pragma unroll
      for (int rr=0; rr<4; rr++){
        const int row = m0 + wm*64 + mt*16 + cq*4 + rr;
        const int col = n0 + wn*64 + nt*16 + cr;
        const long oi = (long)row*ldo + col;
        const float val = acc[mt][nt][rr];
        if constexpr (EPI == EPI_F32){
          ((float*)Out)[oi] = val;
        } else if constexpr (EPI == EPI_BF16){
          ((u16*)Out)[oi] = f2b(val);
        } else if constexpr (EPI == EPI_TANH){
          ((u16*)Out)[oi] = f2b(tanhf(val));
        } else if constexpr (EPI == EPI_SILU){
          ((u16*)Out)[oi] = f2b(val / (1.f + expf(-val)));
        } else if constexpr (EPI == EPI_MIX){
          const float xv  = aux0[oi];
          const float xxv = b2f(aux1[oi]);
          ((u16*)Out)[oi] = f2b(fmaf(xxv, aux2[col] + val, xv));
        } else { // EPI_DECAY: decay = exp(-exp(val + time_decay[col]))
          ((float*)Out)[oi] = expf(-expf(val + aux0[col]));
        }
      }
    }
  }
}

// ---------------- WKV6 scan + groupnorm + *g ----------------
// One block per (b,h); 4 waves split j, 16 j each, lane = i.
// Hybrid of R2/R3 designs:
//  - chunk of 16 steps staged into LDS with coalesced global loads (fast)
//  - per-step path: wave-uniform ds_read_b128 (bank-broadcast, cheap) +
//    per-lane v read + 48 VALU; NO barrier, NO global load in the step loop
//  - cross-wave y-combine + groupnorm deferred to once per chunk
// (R3 failed because per-step wave-uniform GLOBAL loads were serialized at
//  full L2/LLC latency — VGPR=64 showed the compiler didn't pipeline.)
__global__ __launch_bounds__(256, 1) void wkv(
    const u16* __restrict__ r, const u16* __restrict__ k, const u16* __restrict__ v,
    const float* __restrict__ dec, const float* __restrict__ faaaa,
    const float* __restrict__ gam, const float* __restrict__ bet,
    const u16* __restrict__ g, u16* __restrict__ act)
{
  const int blk = blockIdx.x;
  const int b = blk >> 5, h = blk & 31;
  const int tid = threadIdx.x;
  const int jg = tid >> 6, lane = tid & 63;
  const int hoff = h * 64;

  float S[16];
  #pragma unroll
  for (int jj=0;jj<16;jj++) S[jj] = 0.f;
  float u[16];
  #pragma unroll
  for (int jj=0;jj<16;jj++) u[jj] = faaaa[hoff + jg*16 + jj];
  const float gmv = gam[hoff + lane], btv = bet[hoff + lane];

  __shared__ float rs[16][64], ks[16][64], dsh[16][64], vs[16][64];
  __shared__ float yred[16][4][64];   // [t-in-chunk][wave][i]

  const long base0 = ((long)b * T_) * C_ + hoff;
  const int joff = jg * 16;
  // staging coords: each thread loads 4 consecutive channels of one t-row
  const int stt = tid >> 4;          // 0..15
  const int scc = (tid & 15) * 4;    // 0..60

  for (int t0 = 0; t0 < T_; t0 += 16){
    __syncthreads();                 // LDS reuse guard (prev chunk epilogue)
    {
      const long gi = base0 + (long)(t0 + stt) * C_ + scc;
      float tmp[4];
      unpack4(r + gi, tmp);  *(float4*)&rs[stt][scc]  = *(float4*)tmp;
      unpack4(k + gi, tmp);  *(float4*)&ks[stt][scc]  = *(float4*)tmp;
      unpack4(v + gi, tmp);  *(float4*)&vs[stt][scc]  = *(float4*)tmp;
      *(float4*)&dsh[stt][scc] = *(const float4*)(dec + gi);
    }
    __syncthreads();
    #pragma unroll 2
    for (int tt = 0; tt < 16; tt++){
      float rv[16], kv[16], dv[16];
      #pragma unroll
      for (int q=0;q<4;q++){
        *(float4*)(rv+q*4) = *(const float4*)&rs[tt][joff+q*4];
        *(float4*)(kv+q*4) = *(const float4*)&ks[tt][joff+q*4];
        *(float4*)(dv+q*4) = *(const float4*)&dsh[tt][joff+q*4];
      }
      const float vi = vs[tt][lane];
      float yp = 0.f;
      #pragma unroll
      for (int jj=0;jj<16;jj++){
        const float p = kv[jj] * vi;
        yp = fmaf(rv[jj], fmaf(u[jj], p, S[jj]), yp);
        S[jj] = fmaf(dv[jj], S[jj], p);
      }
      yred[tt][jg][lane] = yp;
    }
    __syncthreads();
    // combine partials + groupnorm + *g : each wave handles 4 timesteps
    #pragma unroll
    for (int q=0;q<4;q++){
      const int tt = jg*4 + q;
      const float y = yred[tt][0][lane] + yred[tt][1][lane]
                    + yred[tt][2][lane] + yred[tt][3][lane];
      float s1 = y, s2 = y*y;
      #pragma unroll
      for (int off=32; off>0; off>>=1){
        s1 += __shfl_xor(s1, off, 64);
        s2 += __shfl_xor(s2, off, 64);
      }
      const float mean = s1 * (1.f/64.f);
      const float var  = s2 * (1.f/64.f) - mean*mean;
      const float yn   = (y - mean) * rsqrtf(var + 6.4e-4f);  // EPS = 1e-5*8^2
      const long  oi   = base0 + (long)(t0 + tt) * C_ + lane;
      const float o    = (yn * gmv + btv) * b2f(g[oi]);
      act[oi] = f2b(o);
    }
  }
}

extern "C" void kernel_launch(void* const* d_in, const int* in_sizes, int n_in,
                              void* d_out, int out_size, void* d_ws, size_t ws_size,
                              hipStream_t stream)
{
  const float* x     = (const float*)d_in[0];
  const float* tmx   = (const float*)d_in[1];
  const float* maaf[5] = {(const float*)d_in[2], (const float*)d_in[3],
                          (const float*)d_in[4], (const float*)d_in[5],
                          (const float*)d_in[6]};
  const float* w1    = (const float*)d_in[7];
  const float* w2    = (const float*)d_in[8];
  const float* td    = (const float*)d_in[9];
  const float* tdw1  = (const float*)d_in[10];
  const float* tdw2  = (const float*)d_in[11];
  const float* faaaa = (const float*)d_in[12];
  const float* Wmat[5] = {(const float*)d_in[13], (const float*)d_in[14],
                          (const float*)d_in[15], (const float*)d_in[16],
                          (const float*)d_in[17]};   // W_r, W_k, W_v, W_g, W_o
  const float* ln_g  = (const float*)d_in[18];
  const float* ln_b  = (const float*)d_in[19];

  // ---- workspace layout: ~151.6 MB total ----
  char* p = (char*)d_ws;
  auto take = [&](size_t bytes)->char*{
    char* q = p; p += (bytes + 255) & ~(size_t)255; return q;
  };
  u16*   w1t  = (u16*)take(256L*2048*2);     // (256 x 2048), rows>=160 zero
  u16*   w2t  = (u16*)take(5L*2048*32*2);    // 5 x (2048 x 32)
  u16*   wd1t = (u16*)take(128L*2048*2);     // (128 x 2048), rows>=64 zero
  u16*   wd2t = (u16*)take(2048L*64*2);      // (2048 x 64)
  u16*   wcur = (u16*)take(WELE*2);          // current weight, bf16 (reused 5x)
  u16*   xxx  = (u16*)take(BTC*2);           // xxx; aliased as mixbuf after a-GEMM
  u16*   xxb  = (u16*)take(BTC*2);           // xx;  aliased as rbuf (r done last)
  u16*   abuf = (u16*)take((long)BT_*256*2); // a = tanh(xxx@w1)
  u16*   hbuf = (u16*)take((long)BT_*128*2); // tanh(xw@tdw1)
  u16*   kbuf = (u16*)take(BTC*2);           // aliased as act (safe: see wkv notes)
  u16*   vbuf = (u16*)take(BTC*2);
  u16*   gbuf = (u16*)take(BTC*2);
  u16*   mixbuf = xxx;            // xxx dead after a-GEMM
  u16*   rbuf   = xxb;            // xxb dead after mix-r epilogue
  u16*   act    = kbuf;           // block (b,h) reads its k rows before writing them
  float* dcy    = (float*)d_out;  // fp32 decay; d_out dead until final GEMM
  (void)in_sizes; (void)n_in; (void)out_size; (void)ws_size;

  // small-weight prep
  tposeA <<<2048, 256, 0, stream>>>(w1,   w1t,  2048, 160, 256);
  tposeW2<<<1280, 256, 0, stream>>>(w2,   w2t);
  tposeA <<<1024, 256, 0, stream>>>(tdw1, wd1t, 2048, 64, 128);
  tposeA <<<512,  256, 0, stream>>>(tdw2, wd2t, 64, 2048, 2048);

  // token shift
  mixA<<<16384, 256, 0, stream>>>(x, tmx, xxx, xxb);

  // a = tanh(xxx @ w1)   (M=8192, N=256(pad), K=2048)
  gemm_bt<EPI_TANH><<<dim3(2,64), 256, 0, stream>>>(xxx, 2048, w1t, 2048, 2048,
      abuf, 256, nullptr, nullptr, nullptr);

  // ---- f = w (decay path) ----
  gemm_bt<EPI_MIX><<<dim3(16,64), 256, 0, stream>>>(abuf + 0*32, 256,
      w2t + 0L*65536, 32, 32, mixbuf, 2048, x, xxb, maaf[0]);
  gemm_bt<EPI_TANH><<<dim3(1,64), 256, 0, stream>>>(mixbuf, 2048, wd1t, 2048, 2048,
      hbuf, 128, nullptr, nullptr, nullptr);
  gemm_bt<EPI_DECAY><<<dim3(16,64), 256, 0, stream>>>(hbuf, 128, wd2t, 64, 64,
      dcy, 2048, td, nullptr, nullptr);

  // ---- f = k ----
  gemm_bt<EPI_MIX><<<dim3(16,64), 256, 0, stream>>>(abuf + 1*32, 256,
      w2t + 1L*65536, 32, 32, mixbuf, 2048, x, xxb, maaf[1]);
  cvt1<<<4096, 256, 0, stream>>>(Wmat[1], wcur);
  gemm_bt<EPI_BF16><<<dim3(16,64), 256, 0, stream>>>(mixbuf, 2048, wcur, 2048, 2048,
      kbuf, 2048, nullptr, nullptr, nullptr);

  // ---- f = v ----
  gemm_bt<EPI_MIX><<<dim3(16,64), 256, 0, stream>>>(abuf + 2*32, 256,
      w2t + 2L*65536, 32, 32, mixbuf, 2048, x, xxb, maaf[2]);
  cvt1<<<4096, 256, 0, stream>>>(Wmat[2], wcur);
  gemm_bt<EPI_BF16><<<dim3(16,64), 256, 0, stream>>>(mixbuf, 2048, wcur, 2048, 2048,
      vbuf, 2048, nullptr, nullptr, nullptr);

  // ---- f = g ----
  gemm_bt<EPI_MIX><<<dim3(16,64), 256, 0, stream>>>(abuf + 4*32, 256,
      w2t + 4L*65536, 32, 32, mixbuf, 2048, x, xxb, maaf[4]);
  cvt1<<<4096, 256, 0, stream>>>(Wmat[3], wcur);
  gemm_bt<EPI_SILU><<<dim3(16,64), 256, 0, stream>>>(mixbuf, 2048, wcur, 2048, 2048,
      gbuf, 2048, nullptr, nullptr, nullptr);

  // ---- f = r (last: frees xxb for rbuf) ----
  gemm_bt<EPI_MIX><<<dim3(16,64), 256, 0, stream>>>(abuf + 3*32, 256,
      w2t + 3L*65536, 32, 32, mixbuf, 2048, x, xxb, maaf[3]);
  cvt1<<<4096, 256, 0, stream>>>(Wmat[0], wcur);
  gemm_bt<EPI_BF16><<<dim3(16,64), 256, 0, stream>>>(mixbuf, 2048, wcur, 2048, 2048,
      rbuf, 2048, nullptr, nullptr, nullptr);

  // ---- wkv scan + groupnorm + *g ----
  wkv<<<128, 256, 0, stream>>>(rbuf, kbuf, vbuf, dcy, faaaa, ln_g, ln_b, gbuf, act);

  // ---- out = act @ W_o^T (fp32) ----
  cvt1<<<4096, 256, 0, stream>>>(Wmat[4], wcur);
  gemm_bt<EPI_F32><<<dim3(16,64), 256, 0, stream>>>(act, 2048, wcur, 2048, 2048,
      d_out, 2048, nullptr, nullptr, nullptr);
}